// Round 1
// baseline (4999.363 us; speedup 1.0000x reference)
//
#include <hip/hip_runtime.h>
#include <hip/hip_bf16.h>
#include <math.h>

#define L_SEQ   1024
#define DMODEL  1024
#define DINNER  2048
#define DSTATE  16
#define DTRANK  64
#define NXP     96      // DTRANK + 2*DSTATE
#define LN_EPS  1e-5f

// ---------------------------------------------------------------------------
// GEMM: C[M,N] = A[M,K] @ W[N,K]^T   (row-major A, W stored (N,K) like torch)
// 64x64 tile, K-step 16, 256 threads, 4x4 micro-tile per thread. fp32 VALU.
// ---------------------------------------------------------------------------
__global__ __launch_bounds__(256)
void gemm_nt(const float* __restrict__ A, const float* __restrict__ W,
             float* __restrict__ C, int M, int N, int K,
             int lda, int ldb, int ldc) {
    __shared__ float As[16][64];
    __shared__ float Bs[16][64];
    const int tid = threadIdx.x;
    const int tx = tid & 15, ty = tid >> 4;
    const int m0 = blockIdx.y * 64, n0 = blockIdx.x * 64;
    const int lr = tid >> 2;          // 0..63 row within tile
    const int lk = (tid & 3) << 2;    // 0,4,8,12 k-offset
    float acc[4][4] = {};

    for (int k0 = 0; k0 < K; k0 += 16) {
        float4 av = make_float4(0.f, 0.f, 0.f, 0.f);
        float4 bv = make_float4(0.f, 0.f, 0.f, 0.f);
        const int am = m0 + lr;
        if (am < M) av = *(const float4*)(A + (size_t)am * lda + k0 + lk);
        const int bn = n0 + lr;
        if (bn < N) bv = *(const float4*)(W + (size_t)bn * ldb + k0 + lk);
        __syncthreads();
        As[lk + 0][lr] = av.x; As[lk + 1][lr] = av.y;
        As[lk + 2][lr] = av.z; As[lk + 3][lr] = av.w;
        Bs[lk + 0][lr] = bv.x; Bs[lk + 1][lr] = bv.y;
        Bs[lk + 2][lr] = bv.z; Bs[lk + 3][lr] = bv.w;
        __syncthreads();
        #pragma unroll
        for (int k = 0; k < 16; ++k) {
            const float4 a = *(const float4*)&As[k][ty << 2];
            const float4 b = *(const float4*)&Bs[k][tx << 2];
            acc[0][0] += a.x * b.x; acc[0][1] += a.x * b.y;
            acc[0][2] += a.x * b.z; acc[0][3] += a.x * b.w;
            acc[1][0] += a.y * b.x; acc[1][1] += a.y * b.y;
            acc[1][2] += a.y * b.z; acc[1][3] += a.y * b.w;
            acc[2][0] += a.z * b.x; acc[2][1] += a.z * b.y;
            acc[2][2] += a.z * b.z; acc[2][3] += a.z * b.w;
            acc[3][0] += a.w * b.x; acc[3][1] += a.w * b.y;
            acc[3][2] += a.w * b.z; acc[3][3] += a.w * b.w;
        }
    }
    #pragma unroll
    for (int i = 0; i < 4; ++i) {
        const int m = m0 + (ty << 2) + i;
        if (m < M) {
            #pragma unroll
            for (int j = 0; j < 4; ++j) {
                const int n = n0 + (tx << 2) + j;
                if (n < N) C[(size_t)m * ldc + n] = acc[i][j];
            }
        }
    }
}

// ---------------------------------------------------------------------------
// Residual add + LayerNorm. One block (256 thr) per row of 1024.
// ---------------------------------------------------------------------------
__global__ __launch_bounds__(256)
void add_ln(const float* __restrict__ h, float* __restrict__ res,
            float* __restrict__ hn, const float* __restrict__ w,
            const float* __restrict__ b, int is_first) {
    const int l = blockIdx.x;
    const int t = threadIdx.x;
    float v[4];
    float s = 0.f, ss = 0.f;
    #pragma unroll
    for (int j = 0; j < 4; ++j) {
        const int d = t + j * 256;
        float x = h[(size_t)l * DMODEL + d];
        if (!is_first) x += res[(size_t)l * DMODEL + d];
        res[(size_t)l * DMODEL + d] = x;
        v[j] = x; s += x; ss += x * x;
    }
    #pragma unroll
    for (int o = 32; o > 0; o >>= 1) {
        s  += __shfl_down(s, o);
        ss += __shfl_down(ss, o);
    }
    __shared__ float sm[4], sm2[4];
    const int wid = t >> 6;
    if ((t & 63) == 0) { sm[wid] = s; sm2[wid] = ss; }
    __syncthreads();
    s  = sm[0] + sm[1] + sm[2] + sm[3];
    ss = sm2[0] + sm2[1] + sm2[2] + sm2[3];
    const float mu  = s * (1.f / DMODEL);
    const float var = ss * (1.f / DMODEL) - mu * mu;
    const float r   = rsqrtf(var + LN_EPS);
    #pragma unroll
    for (int j = 0; j < 4; ++j) {
        const int d = t + j * 256;
        hn[(size_t)l * DMODEL + d] = (v[j] - mu) * r * w[d] + b[d];
    }
}

// ---------------------------------------------------------------------------
// Causal depthwise conv (4 taps) + bias + SiLU on the x-half of xz.
// ---------------------------------------------------------------------------
__global__ __launch_bounds__(256)
void conv_silu(const float* __restrict__ xz, float* __restrict__ xc,
               const float* __restrict__ cw, const float* __restrict__ cb) {
    const int idx = blockIdx.x * 256 + threadIdx.x;   // l*DINNER + d
    const int l = idx >> 11;
    const int d = idx & (DINNER - 1);
    float acc = cb[d];
    #pragma unroll
    for (int k = 0; k < 4; ++k) {
        const int ls = l + k - 3;
        if (ls >= 0) acc += cw[d * 4 + k] * xz[(size_t)ls * (2 * DINNER) + d];
    }
    const float sig = 1.f / (1.f + expf(-acc));
    xc[idx] = acc * sig;
}

// ---------------------------------------------------------------------------
// delta = softplus(delta + bias)
// ---------------------------------------------------------------------------
__global__ __launch_bounds__(256)
void softplus_bias(float* __restrict__ delta, const float* __restrict__ bias) {
    const int idx = blockIdx.x * 256 + threadIdx.x;
    const int d = idx & (DINNER - 1);
    const float v = delta[idx] + bias[d];
    delta[idx] = (v > 20.f) ? v : log1pf(expf(v));
}

// ---------------------------------------------------------------------------
// Selective scan. Thread = (channel d, state s). 16 channels / block.
// Fuses +x*D skip and *silu(z) gate into the y write.
// ---------------------------------------------------------------------------
__global__ __launch_bounds__(256)
void ssm_scan(const float* __restrict__ delta, const float* __restrict__ xc,
              const float* __restrict__ xdbl, const float* __restrict__ xz,
              const float* __restrict__ alog, const float* __restrict__ dsk,
              float* __restrict__ y) {
    const int t = threadIdx.x;
    const int s = t & 15;
    const int d = blockIdx.x * 16 + (t >> 4);
    const float A  = -expf(alog[d * DSTATE + s]);
    const float Dk = dsk[d];
    float hst = 0.f;
    for (int l = 0; l < L_SEQ; ++l) {
        const float dl = delta[(size_t)l * DINNER + d];
        const float xl = xc[(size_t)l * DINNER + d];
        const float Bl = xdbl[(size_t)l * NXP + DTRANK + s];
        const float Cl = xdbl[(size_t)l * NXP + DTRANK + DSTATE + s];
        hst = expf(dl * A) * hst + dl * Bl * xl;
        float c = hst * Cl;
        c += __shfl_xor(c, 1, 16);
        c += __shfl_xor(c, 2, 16);
        c += __shfl_xor(c, 4, 16);
        c += __shfl_xor(c, 8, 16);
        if (s == 0) {
            const float zl = xz[(size_t)l * (2 * DINNER) + DINNER + d];
            const float sig = 1.f / (1.f + expf(-zl));
            y[(size_t)l * DINNER + d] = (c + xl * Dk) * (zl * sig);
        }
    }
}

// ---------------------------------------------------------------------------
extern "C" void kernel_launch(void* const* d_in, const int* in_sizes, int n_in,
                              void* d_out, int out_size, void* d_ws, size_t ws_size,
                              hipStream_t stream) {
    const float* input   = (const float*)d_in[0];
    const float* input_w = (const float*)d_in[2];
    const float* norm_w  = (const float*)d_in[3];
    const float* norm_b  = (const float*)d_in[4];
    const float* ipw     = (const float*)d_in[5];
    const float* cw      = (const float*)d_in[6];
    const float* cb      = (const float*)d_in[7];
    const float* xpw     = (const float*)d_in[8];
    const float* dtw     = (const float*)d_in[9];
    const float* dtb     = (const float*)d_in[10];
    const float* alog    = (const float*)d_in[11];
    const float* dsk     = (const float*)d_in[12];
    const float* opw     = (const float*)d_in[13];
    float* out = (float*)d_out;

    float* ws    = (float*)d_ws;
    float* h     = ws;                       // 1M floats
    float* res   = h    + (1u << 20);        // 1M
    float* hn    = res  + (1u << 20);        // 1M
    float* xz    = hn   + (1u << 20);        // 4M
    float* xc    = xz   + (4u << 20);        // 2M
    float* xdbl  = xc   + (2u << 20);        // L*96
    float* delta = xdbl + (L_SEQ * NXP);     // 2M
    float* yb    = delta + (2u << 20);       // 2M

    const dim3 blk(256);

    // h = input @ input_w^T   (M=1024, N=1024, K=512)
    gemm_nt<<<dim3(DMODEL / 64, L_SEQ / 64), blk, 0, stream>>>(
        input, input_w, h, L_SEQ, DMODEL, 512, 512, 512, DMODEL);

    for (int i = 0; i < 4; ++i) {
        add_ln<<<L_SEQ, 256, 0, stream>>>(
            h, res, hn, norm_w + i * DMODEL, norm_b + i * DMODEL, i == 0);

        // xz = hn @ ipw^T   (M=1024, N=4096, K=1024)
        gemm_nt<<<dim3(2 * DINNER / 64, L_SEQ / 64), blk, 0, stream>>>(
            hn, ipw + (size_t)i * 2 * DINNER * DMODEL, xz,
            L_SEQ, 2 * DINNER, DMODEL, DMODEL, DMODEL, 2 * DINNER);

        conv_silu<<<(L_SEQ * DINNER) / 256, 256, 0, stream>>>(
            xz, xc, cw + i * DINNER * 4, cb + i * DINNER);

        // xdbl = xc @ xpw^T   (M=1024, N=96, K=2048)
        gemm_nt<<<dim3(2, L_SEQ / 64), blk, 0, stream>>>(
            xc, xpw + (size_t)i * NXP * DINNER, xdbl,
            L_SEQ, NXP, DINNER, DINNER, DINNER, NXP);

        // delta = xdbl[:, :64] @ dtw^T   (M=1024, N=2048, K=64)
        gemm_nt<<<dim3(DINNER / 64, L_SEQ / 64), blk, 0, stream>>>(
            xdbl, dtw + (size_t)i * DINNER * DTRANK, delta,
            L_SEQ, DINNER, DTRANK, NXP, DTRANK, DINNER);

        softplus_bias<<<(L_SEQ * DINNER) / 256, 256, 0, stream>>>(
            delta, dtb + i * DINNER);

        ssm_scan<<<DINNER / 16, 256, 0, stream>>>(
            delta, xc, xdbl, xz, alog + i * DINNER * DSTATE, dsk + i * DINNER, yb);

        // out = y @ opw^T   (M=1024, N=1024, K=2048)
        float* dst = (i == 3) ? out : h;
        gemm_nt<<<dim3(DMODEL / 64, L_SEQ / 64), blk, 0, stream>>>(
            yb, opw + (size_t)i * DMODEL * DINNER, dst,
            L_SEQ, DMODEL, DINNER, DINNER, DINNER, DMODEL);
    }
}

// Round 2
// 2076.925 us; speedup vs baseline: 2.4071x; 2.4071x over previous
//
#include <hip/hip_runtime.h>
#include <hip/hip_bf16.h>
#include <math.h>

#define L_SEQ   1024
#define DMODEL  1024
#define DINNER  2048
#define DSTATE  16
#define DTRANK  64
#define NXP     96      // DTRANK + 2*DSTATE
#define LN_EPS  1e-5f
#define CHUNK   32
#define NCHUNK  (L_SEQ / CHUNK)

// ---------------------------------------------------------------------------
// GEMM: C[M,N] = A[M,K] @ W[N,K]^T   (row-major A, W stored (N,K) like torch)
// 64x64 tile, K-step 16, 256 threads, 4x4 micro-tile per thread. fp32 VALU.
// ---------------------------------------------------------------------------
__global__ __launch_bounds__(256)
void gemm_nt(const float* __restrict__ A, const float* __restrict__ W,
             float* __restrict__ C, int M, int N, int K,
             int lda, int ldb, int ldc) {
    __shared__ float As[16][64];
    __shared__ float Bs[16][64];
    const int tid = threadIdx.x;
    const int tx = tid & 15, ty = tid >> 4;
    const int m0 = blockIdx.y * 64, n0 = blockIdx.x * 64;
    const int lr = tid >> 2;          // 0..63 row within tile
    const int lk = (tid & 3) << 2;    // 0,4,8,12 k-offset
    float acc[4][4] = {};

    for (int k0 = 0; k0 < K; k0 += 16) {
        float4 av = make_float4(0.f, 0.f, 0.f, 0.f);
        float4 bv = make_float4(0.f, 0.f, 0.f, 0.f);
        const int am = m0 + lr;
        if (am < M) av = *(const float4*)(A + (size_t)am * lda + k0 + lk);
        const int bn = n0 + lr;
        if (bn < N) bv = *(const float4*)(W + (size_t)bn * ldb + k0 + lk);
        __syncthreads();
        As[lk + 0][lr] = av.x; As[lk + 1][lr] = av.y;
        As[lk + 2][lr] = av.z; As[lk + 3][lr] = av.w;
        Bs[lk + 0][lr] = bv.x; Bs[lk + 1][lr] = bv.y;
        Bs[lk + 2][lr] = bv.z; Bs[lk + 3][lr] = bv.w;
        __syncthreads();
        #pragma unroll
        for (int k = 0; k < 16; ++k) {
            const float4 a = *(const float4*)&As[k][ty << 2];
            const float4 b = *(const float4*)&Bs[k][tx << 2];
            acc[0][0] += a.x * b.x; acc[0][1] += a.x * b.y;
            acc[0][2] += a.x * b.z; acc[0][3] += a.x * b.w;
            acc[1][0] += a.y * b.x; acc[1][1] += a.y * b.y;
            acc[1][2] += a.y * b.z; acc[1][3] += a.y * b.w;
            acc[2][0] += a.z * b.x; acc[2][1] += a.z * b.y;
            acc[2][2] += a.z * b.z; acc[2][3] += a.z * b.w;
            acc[3][0] += a.w * b.x; acc[3][1] += a.w * b.y;
            acc[3][2] += a.w * b.z; acc[3][3] += a.w * b.w;
        }
    }
    #pragma unroll
    for (int i = 0; i < 4; ++i) {
        const int m = m0 + (ty << 2) + i;
        if (m < M) {
            #pragma unroll
            for (int j = 0; j < 4; ++j) {
                const int n = n0 + (tx << 2) + j;
                if (n < N) C[(size_t)m * ldc + n] = acc[i][j];
            }
        }
    }
}

// ---------------------------------------------------------------------------
// Residual add + LayerNorm. One block (256 thr) per row of 1024.
// ---------------------------------------------------------------------------
__global__ __launch_bounds__(256)
void add_ln(const float* __restrict__ h, float* __restrict__ res,
            float* __restrict__ hn, const float* __restrict__ w,
            const float* __restrict__ b, int is_first) {
    const int l = blockIdx.x;
    const int t = threadIdx.x;
    float v[4];
    float s = 0.f, ss = 0.f;
    #pragma unroll
    for (int j = 0; j < 4; ++j) {
        const int d = t + j * 256;
        float x = h[(size_t)l * DMODEL + d];
        if (!is_first) x += res[(size_t)l * DMODEL + d];
        res[(size_t)l * DMODEL + d] = x;
        v[j] = x; s += x; ss += x * x;
    }
    #pragma unroll
    for (int o = 32; o > 0; o >>= 1) {
        s  += __shfl_down(s, o);
        ss += __shfl_down(ss, o);
    }
    __shared__ float sm[4], sm2[4];
    const int wid = t >> 6;
    if ((t & 63) == 0) { sm[wid] = s; sm2[wid] = ss; }
    __syncthreads();
    s  = sm[0] + sm[1] + sm[2] + sm[3];
    ss = sm2[0] + sm2[1] + sm2[2] + sm2[3];
    const float mu  = s * (1.f / DMODEL);
    const float var = ss * (1.f / DMODEL) - mu * mu;
    const float r   = rsqrtf(var + LN_EPS);
    #pragma unroll
    for (int j = 0; j < 4; ++j) {
        const int d = t + j * 256;
        hn[(size_t)l * DMODEL + d] = (v[j] - mu) * r * w[d] + b[d];
    }
}

// ---------------------------------------------------------------------------
// Causal depthwise conv (4 taps) + bias + SiLU on the x-half of xz.
// ---------------------------------------------------------------------------
__global__ __launch_bounds__(256)
void conv_silu(const float* __restrict__ xz, float* __restrict__ xc,
               const float* __restrict__ cw, const float* __restrict__ cb) {
    const int idx = blockIdx.x * 256 + threadIdx.x;   // l*DINNER + d
    const int l = idx >> 11;
    const int d = idx & (DINNER - 1);
    float acc = cb[d];
    #pragma unroll
    for (int k = 0; k < 4; ++k) {
        const int ls = l + k - 3;
        if (ls >= 0) acc += cw[d * 4 + k] * xz[(size_t)ls * (2 * DINNER) + d];
    }
    const float sig = 1.f / (1.f + expf(-acc));
    xc[idx] = acc * sig;
}

// ---------------------------------------------------------------------------
// delta = softplus(delta + bias)
// ---------------------------------------------------------------------------
__global__ __launch_bounds__(256)
void softplus_bias(float* __restrict__ delta, const float* __restrict__ bias) {
    const int idx = blockIdx.x * 256 + threadIdx.x;
    const int d = idx & (DINNER - 1);
    const float v = delta[idx] + bias[d];
    delta[idx] = (v > 20.f) ? v : log1pf(expf(v));
}

// ---------------------------------------------------------------------------
// Chunk-parallel selective scan. One block (512 thr) per channel d.
// Thread (s, c): s = state 0..15, c = chunk 0..31 (32 timesteps each).
// Phase 1: local scan (h0=0) accumulating (prod dA, h_local).
// Phase 2: 16 threads serially combine the 32 chunk summaries in LDS.
// Phase 3: rescan with true chunk-entry state; fused C-reduce + D-skip +
//          silu(z) gate on the write of y.
// ---------------------------------------------------------------------------
__global__ __launch_bounds__(512)
void ssm_scan_chunked(const float* __restrict__ delta,
                      const float* __restrict__ xc,
                      const float* __restrict__ xdbl,
                      const float* __restrict__ xz,
                      const float* __restrict__ alog,
                      const float* __restrict__ dsk,
                      float* __restrict__ y) {
    const int d = blockIdx.x;
    const int t = threadIdx.x;
    const int s = t & 15;
    const int c = t >> 4;          // chunk index 0..31

    __shared__ float sdl[L_SEQ];
    __shared__ float sxl[L_SEQ];
    __shared__ float saprod[NCHUNK][DSTATE];
    __shared__ float shloc[NCHUNK][DSTATE];
    __shared__ float shstart[NCHUNK][DSTATE];

    // Stage delta[:,d] and xc[:,d] once (kills 16x redundant broadcasts).
    for (int l = t; l < L_SEQ; l += 512) {
        sdl[l] = delta[(size_t)l * DINNER + d];
        sxl[l] = xc[(size_t)l * DINNER + d];
    }
    __syncthreads();

    const float A  = -expf(alog[d * DSTATE + s]);
    const int   l0 = c * CHUNK;

    // Phase 1: local scan with h0 = 0.
    float aprod = 1.f, h = 0.f;
    #pragma unroll 4
    for (int j = 0; j < CHUNK; ++j) {
        const int l = l0 + j;
        const float dl = sdl[l];
        const float Bl = xdbl[(size_t)l * NXP + DTRANK + s];
        const float da = __expf(dl * A);
        h = da * h + dl * Bl * sxl[l];
        aprod *= da;
    }
    saprod[c][s] = aprod;
    shloc[c][s]  = h;
    __syncthreads();

    // Phase 2: serial combine across chunks (16 threads, 32 steps).
    if (c == 0) {
        float hs = 0.f;
        for (int cc = 0; cc < NCHUNK; ++cc) {
            shstart[cc][s] = hs;
            hs = saprod[cc][s] * hs + shloc[cc][s];
        }
    }
    __syncthreads();

    // Phase 3: rescan with true entry state, produce y.
    h = shstart[c][s];
    const float Dk = dsk[d];
    for (int j = 0; j < CHUNK; ++j) {
        const int l = l0 + j;
        const float dl = sdl[l];
        const float xl = sxl[l];
        const float Bl = xdbl[(size_t)l * NXP + DTRANK + s];
        const float Cl = xdbl[(size_t)l * NXP + DTRANK + DSTATE + s];
        h = __expf(dl * A) * h + dl * Bl * xl;
        float cch = h * Cl;
        cch += __shfl_xor(cch, 1, 16);
        cch += __shfl_xor(cch, 2, 16);
        cch += __shfl_xor(cch, 4, 16);
        cch += __shfl_xor(cch, 8, 16);
        if (s == 0) {
            const float zl  = xz[(size_t)l * (2 * DINNER) + DINNER + d];
            const float sig = 1.f / (1.f + __expf(-zl));
            y[(size_t)l * DINNER + d] = (cch + xl * Dk) * (zl * sig);
        }
    }
}

// ---------------------------------------------------------------------------
extern "C" void kernel_launch(void* const* d_in, const int* in_sizes, int n_in,
                              void* d_out, int out_size, void* d_ws, size_t ws_size,
                              hipStream_t stream) {
    const float* input   = (const float*)d_in[0];
    const float* input_w = (const float*)d_in[2];
    const float* norm_w  = (const float*)d_in[3];
    const float* norm_b  = (const float*)d_in[4];
    const float* ipw     = (const float*)d_in[5];
    const float* cw      = (const float*)d_in[6];
    const float* cb      = (const float*)d_in[7];
    const float* xpw     = (const float*)d_in[8];
    const float* dtw     = (const float*)d_in[9];
    const float* dtb     = (const float*)d_in[10];
    const float* alog    = (const float*)d_in[11];
    const float* dsk     = (const float*)d_in[12];
    const float* opw     = (const float*)d_in[13];
    float* out = (float*)d_out;

    float* ws    = (float*)d_ws;
    float* h     = ws;                       // 1M floats
    float* res   = h    + (1u << 20);        // 1M
    float* hn    = res  + (1u << 20);        // 1M
    float* xz    = hn   + (1u << 20);        // 4M
    float* xc    = xz   + (4u << 20);        // 2M
    float* xdbl  = xc   + (2u << 20);        // L*96
    float* delta = xdbl + (L_SEQ * NXP);     // 2M
    float* yb    = delta + (2u << 20);       // 2M

    const dim3 blk(256);

    // h = input @ input_w^T   (M=1024, N=1024, K=512)
    gemm_nt<<<dim3(DMODEL / 64, L_SEQ / 64), blk, 0, stream>>>(
        input, input_w, h, L_SEQ, DMODEL, 512, 512, 512, DMODEL);

    for (int i = 0; i < 4; ++i) {
        add_ln<<<L_SEQ, 256, 0, stream>>>(
            h, res, hn, norm_w + i * DMODEL, norm_b + i * DMODEL, i == 0);

        // xz = hn @ ipw^T   (M=1024, N=4096, K=1024)
        gemm_nt<<<dim3(2 * DINNER / 64, L_SEQ / 64), blk, 0, stream>>>(
            hn, ipw + (size_t)i * 2 * DINNER * DMODEL, xz,
            L_SEQ, 2 * DINNER, DMODEL, DMODEL, DMODEL, 2 * DINNER);

        conv_silu<<<(L_SEQ * DINNER) / 256, 256, 0, stream>>>(
            xz, xc, cw + i * DINNER * 4, cb + i * DINNER);

        // xdbl = xc @ xpw^T   (M=1024, N=96, K=2048)
        gemm_nt<<<dim3(2, L_SEQ / 64), blk, 0, stream>>>(
            xc, xpw + (size_t)i * NXP * DINNER, xdbl,
            L_SEQ, NXP, DINNER, DINNER, DINNER, NXP);

        // delta = xdbl[:, :64] @ dtw^T   (M=1024, N=2048, K=64)
        gemm_nt<<<dim3(DINNER / 64, L_SEQ / 64), blk, 0, stream>>>(
            xdbl, dtw + (size_t)i * DINNER * DTRANK, delta,
            L_SEQ, DINNER, DTRANK, NXP, DTRANK, DINNER);

        softplus_bias<<<(L_SEQ * DINNER) / 256, 256, 0, stream>>>(
            delta, dtb + i * DINNER);

        ssm_scan_chunked<<<DINNER, 512, 0, stream>>>(
            delta, xc, xdbl, xz, alog + i * DINNER * DSTATE, dsk + i * DINNER, yb);

        // out = y @ opw^T   (M=1024, N=1024, K=2048)
        float* dst = (i == 3) ? out : h;
        gemm_nt<<<dim3(DMODEL / 64, L_SEQ / 64), blk, 0, stream>>>(
            yb, opw + (size_t)i * DMODEL * DINNER, dst,
            L_SEQ, DMODEL, DINNER, DINNER, DINNER, DMODEL);
    }
}

// Round 3
// 1071.988 us; speedup vs baseline: 4.6636x; 1.9375x over previous
//
#include <hip/hip_runtime.h>
#include <hip/hip_bf16.h>
#include <math.h>

#define L_SEQ   1024
#define DMODEL  1024
#define DINNER  2048
#define DSTATE  16
#define DTRANK  64
#define NXP     96      // DTRANK + 2*DSTATE
#define LN_EPS  1e-5f
#define CHUNK   32
#define NCHUNK  (L_SEQ / CHUNK)

typedef __bf16 bf16x8 __attribute__((ext_vector_type(8)));
typedef float  f32x4  __attribute__((ext_vector_type(4)));

// ---------------------------------------------------------------------------
// bf16 MFMA GEMM (m97 structure): C[M,N] = A[M,K] @ W[N,K]^T, fp32 out.
// 128x128 tile, 256 thr = 4 waves (2x2 of 64x64), BK=32, global_load_lds x16.
// Requires M,N % 128 == 0, K % 32 == 0.
// ---------------------------------------------------------------------------
__global__ __launch_bounds__(256)
void gemm_bt_bf16(const __hip_bfloat16* __restrict__ A,
                  const __hip_bfloat16* __restrict__ W,
                  float* __restrict__ C,
                  int K, int lda, int ldb, int ldc) {
    __shared__ __hip_bfloat16 As[128][32];   // 8 KB
    __shared__ __hip_bfloat16 Bs[128][32];   // 8 KB
    const int tid  = threadIdx.x;
    const int lane = tid & 63;
    const int wave = tid >> 6;
    const int m0 = blockIdx.y * 128, n0 = blockIdx.x * 128;
    const int wm = (wave >> 1) * 64, wn = (wave & 1) * 64;
    // staging: thread t -> row t/4, k-offset (t%4)*8; LDS offset = t*16 bytes
    const int srow = tid >> 2, skcol = (tid & 3) << 3;
    // fragment read: A[m=lane&15][k=(lane>>4)*8 + j]
    const int fm = lane & 15, fk = (lane >> 4) << 3;

    f32x4 acc[4][4] = {};

    const __hip_bfloat16* Ap0 = A + (size_t)(m0 + srow) * lda + skcol;
    const __hip_bfloat16* Ap1 = Ap0 + (size_t)64 * lda;
    const __hip_bfloat16* Wp0 = W + (size_t)(n0 + srow) * ldb + skcol;
    const __hip_bfloat16* Wp1 = Wp0 + (size_t)64 * ldb;

    for (int k0 = 0; k0 < K; k0 += 32) {
        __syncthreads();   // prior tile's LDS reads done before overwrite
        __builtin_amdgcn_global_load_lds(
            (const __attribute__((address_space(1))) unsigned int*)(Ap0 + k0),
            (__attribute__((address_space(3))) unsigned int*)&As[srow][skcol], 16, 0, 0);
        __builtin_amdgcn_global_load_lds(
            (const __attribute__((address_space(1))) unsigned int*)(Ap1 + k0),
            (__attribute__((address_space(3))) unsigned int*)&As[64 + srow][skcol], 16, 0, 0);
        __builtin_amdgcn_global_load_lds(
            (const __attribute__((address_space(1))) unsigned int*)(Wp0 + k0),
            (__attribute__((address_space(3))) unsigned int*)&Bs[srow][skcol], 16, 0, 0);
        __builtin_amdgcn_global_load_lds(
            (const __attribute__((address_space(1))) unsigned int*)(Wp1 + k0),
            (__attribute__((address_space(3))) unsigned int*)&Bs[64 + srow][skcol], 16, 0, 0);
        __syncthreads();   // vmcnt(0) drain + barrier

        bf16x8 af[4], bfr[4];
        #pragma unroll
        for (int i = 0; i < 4; ++i) {
            af[i]  = *(const bf16x8*)&As[wm + i * 16 + fm][fk];
            bfr[i] = *(const bf16x8*)&Bs[wn + i * 16 + fm][fk];
        }
        #pragma unroll
        for (int mt = 0; mt < 4; ++mt)
            #pragma unroll
            for (int nt = 0; nt < 4; ++nt)
                acc[mt][nt] = __builtin_amdgcn_mfma_f32_16x16x32_bf16(
                    af[mt], bfr[nt], acc[mt][nt], 0, 0, 0);
    }

    // C/D layout: col = lane&15, row = (lane>>4)*4 + reg   [m89/m91 verified]
    const int crow = (lane >> 4) << 2;
    const int ccol = lane & 15;
    #pragma unroll
    for (int mt = 0; mt < 4; ++mt)
        #pragma unroll
        for (int nt = 0; nt < 4; ++nt) {
            float* cp = C + (size_t)(m0 + wm + mt * 16 + crow) * ldc
                          + n0 + wn + nt * 16 + ccol;
            #pragma unroll
            for (int r = 0; r < 4; ++r) cp[(size_t)r * ldc] = acc[mt][nt][r];
        }
}

// ---------------------------------------------------------------------------
// fp32 tiled GEMM (kept for dt_proj + first projection).
// ---------------------------------------------------------------------------
__global__ __launch_bounds__(256)
void gemm_nt(const float* __restrict__ A, const float* __restrict__ W,
             float* __restrict__ C, int M, int N, int K,
             int lda, int ldb, int ldc) {
    __shared__ float As[16][64];
    __shared__ float Bs[16][64];
    const int tid = threadIdx.x;
    const int tx = tid & 15, ty = tid >> 4;
    const int m0 = blockIdx.y * 64, n0 = blockIdx.x * 64;
    const int lr = tid >> 2;
    const int lk = (tid & 3) << 2;
    float acc[4][4] = {};

    for (int k0 = 0; k0 < K; k0 += 16) {
        float4 av = make_float4(0.f, 0.f, 0.f, 0.f);
        float4 bv = make_float4(0.f, 0.f, 0.f, 0.f);
        const int am = m0 + lr;
        if (am < M) av = *(const float4*)(A + (size_t)am * lda + k0 + lk);
        const int bn = n0 + lr;
        if (bn < N) bv = *(const float4*)(W + (size_t)bn * ldb + k0 + lk);
        __syncthreads();
        As[lk + 0][lr] = av.x; As[lk + 1][lr] = av.y;
        As[lk + 2][lr] = av.z; As[lk + 3][lr] = av.w;
        Bs[lk + 0][lr] = bv.x; Bs[lk + 1][lr] = bv.y;
        Bs[lk + 2][lr] = bv.z; Bs[lk + 3][lr] = bv.w;
        __syncthreads();
        #pragma unroll
        for (int k = 0; k < 16; ++k) {
            const float4 a = *(const float4*)&As[k][ty << 2];
            const float4 b = *(const float4*)&Bs[k][tx << 2];
            acc[0][0] += a.x * b.x; acc[0][1] += a.x * b.y;
            acc[0][2] += a.x * b.z; acc[0][3] += a.x * b.w;
            acc[1][0] += a.y * b.x; acc[1][1] += a.y * b.y;
            acc[1][2] += a.y * b.z; acc[1][3] += a.y * b.w;
            acc[2][0] += a.z * b.x; acc[2][1] += a.z * b.y;
            acc[2][2] += a.z * b.z; acc[2][3] += a.z * b.w;
            acc[3][0] += a.w * b.x; acc[3][1] += a.w * b.y;
            acc[3][2] += a.w * b.z; acc[3][3] += a.w * b.w;
        }
    }
    #pragma unroll
    for (int i = 0; i < 4; ++i) {
        const int m = m0 + (ty << 2) + i;
        if (m < M) {
            #pragma unroll
            for (int j = 0; j < 4; ++j) {
                const int n = n0 + (tx << 2) + j;
                if (n < N) C[(size_t)m * ldc + n] = acc[i][j];
            }
        }
    }
}

// ---------------------------------------------------------------------------
// fp32 split-K GEMM for the skinny x_proj (N=96): grid.z slices K,
// fp32 atomicAdd epilogue (C must be zeroed first).
// ---------------------------------------------------------------------------
__global__ __launch_bounds__(256)
void gemm_nt_splitk(const float* __restrict__ A, const float* __restrict__ W,
                    float* __restrict__ C, int M, int N, int K,
                    int lda, int ldb, int ldc, int kchunk) {
    __shared__ float As[16][64];
    __shared__ float Bs[16][64];
    const int tid = threadIdx.x;
    const int tx = tid & 15, ty = tid >> 4;
    const int m0 = blockIdx.y * 64, n0 = blockIdx.x * 64;
    const int k0s = blockIdx.z * kchunk;
    const int lr = tid >> 2;
    const int lk = (tid & 3) << 2;
    float acc[4][4] = {};

    for (int k0 = k0s; k0 < k0s + kchunk; k0 += 16) {
        float4 av = make_float4(0.f, 0.f, 0.f, 0.f);
        float4 bv = make_float4(0.f, 0.f, 0.f, 0.f);
        const int am = m0 + lr;
        if (am < M) av = *(const float4*)(A + (size_t)am * lda + k0 + lk);
        const int bn = n0 + lr;
        if (bn < N) bv = *(const float4*)(W + (size_t)bn * ldb + k0 + lk);
        __syncthreads();
        As[lk + 0][lr] = av.x; As[lk + 1][lr] = av.y;
        As[lk + 2][lr] = av.z; As[lk + 3][lr] = av.w;
        Bs[lk + 0][lr] = bv.x; Bs[lk + 1][lr] = bv.y;
        Bs[lk + 2][lr] = bv.z; Bs[lk + 3][lr] = bv.w;
        __syncthreads();
        #pragma unroll
        for (int k = 0; k < 16; ++k) {
            const float4 a = *(const float4*)&As[k][ty << 2];
            const float4 b = *(const float4*)&Bs[k][tx << 2];
            acc[0][0] += a.x * b.x; acc[0][1] += a.x * b.y;
            acc[0][2] += a.x * b.z; acc[0][3] += a.x * b.w;
            acc[1][0] += a.y * b.x; acc[1][1] += a.y * b.y;
            acc[1][2] += a.y * b.z; acc[1][3] += a.y * b.w;
            acc[2][0] += a.z * b.x; acc[2][1] += a.z * b.y;
            acc[2][2] += a.z * b.z; acc[2][3] += a.z * b.w;
            acc[3][0] += a.w * b.x; acc[3][1] += a.w * b.y;
            acc[3][2] += a.w * b.z; acc[3][3] += a.w * b.w;
        }
    }
    #pragma unroll
    for (int i = 0; i < 4; ++i) {
        const int m = m0 + (ty << 2) + i;
        if (m < M) {
            #pragma unroll
            for (int j = 0; j < 4; ++j) {
                const int n = n0 + (tx << 2) + j;
                if (n < N) atomicAdd(&C[(size_t)m * ldc + n], acc[i][j]);
            }
        }
    }
}

// ---------------------------------------------------------------------------
__global__ __launch_bounds__(256)
void zero_f32(float* __restrict__ p, int n) {
    const int i = blockIdx.x * 256 + threadIdx.x;
    if (i < n) p[i] = 0.f;
}

// cast fp32 -> bf16, 4 elems/thread (n % 4 == 0)
__global__ __launch_bounds__(256)
void cast_f32_bf16(const float* __restrict__ in, __hip_bfloat16* __restrict__ out,
                   int n4) {
    const int i = blockIdx.x * 256 + threadIdx.x;
    if (i < n4) {
        const float4 v = *(const float4*)(in + (size_t)i * 4);
        __hip_bfloat16 h0 = __float2bfloat16(v.x), h1 = __float2bfloat16(v.y);
        __hip_bfloat16 h2 = __float2bfloat16(v.z), h3 = __float2bfloat16(v.w);
        ushort4 p;
        p.x = *(unsigned short*)&h0; p.y = *(unsigned short*)&h1;
        p.z = *(unsigned short*)&h2; p.w = *(unsigned short*)&h3;
        *(ushort4*)((unsigned short*)out + (size_t)i * 4) = p;
    }
}

// ---------------------------------------------------------------------------
// Residual add + LayerNorm -> bf16 output. One block (256 thr) per row.
// ---------------------------------------------------------------------------
__global__ __launch_bounds__(256)
void add_ln(const float* __restrict__ h, float* __restrict__ res,
            __hip_bfloat16* __restrict__ hn, const float* __restrict__ w,
            const float* __restrict__ b, int is_first) {
    const int l = blockIdx.x;
    const int t = threadIdx.x;
    float v[4];
    float s = 0.f, ss = 0.f;
    #pragma unroll
    for (int j = 0; j < 4; ++j) {
        const int d = t + j * 256;
        float x = h[(size_t)l * DMODEL + d];
        if (!is_first) x += res[(size_t)l * DMODEL + d];
        res[(size_t)l * DMODEL + d] = x;
        v[j] = x; s += x; ss += x * x;
    }
    #pragma unroll
    for (int o = 32; o > 0; o >>= 1) {
        s  += __shfl_down(s, o);
        ss += __shfl_down(ss, o);
    }
    __shared__ float sm[4], sm2[4];
    const int wid = t >> 6;
    if ((t & 63) == 0) { sm[wid] = s; sm2[wid] = ss; }
    __syncthreads();
    s  = sm[0] + sm[1] + sm[2] + sm[3];
    ss = sm2[0] + sm2[1] + sm2[2] + sm2[3];
    const float mu  = s * (1.f / DMODEL);
    const float var = ss * (1.f / DMODEL) - mu * mu;
    const float r   = rsqrtf(var + LN_EPS);
    #pragma unroll
    for (int j = 0; j < 4; ++j) {
        const int d = t + j * 256;
        hn[(size_t)l * DMODEL + d] = __float2bfloat16((v[j] - mu) * r * w[d] + b[d]);
    }
}

// ---------------------------------------------------------------------------
__global__ __launch_bounds__(256)
void conv_silu(const float* __restrict__ xz, float* __restrict__ xc,
               const float* __restrict__ cw, const float* __restrict__ cb) {
    const int idx = blockIdx.x * 256 + threadIdx.x;
    const int l = idx >> 11;
    const int d = idx & (DINNER - 1);
    float acc = cb[d];
    #pragma unroll
    for (int k = 0; k < 4; ++k) {
        const int ls = l + k - 3;
        if (ls >= 0) acc += cw[d * 4 + k] * xz[(size_t)ls * (2 * DINNER) + d];
    }
    const float sig = 1.f / (1.f + expf(-acc));
    xc[idx] = acc * sig;
}

// ---------------------------------------------------------------------------
__global__ __launch_bounds__(256)
void softplus_bias(float* __restrict__ delta, const float* __restrict__ bias) {
    const int idx = blockIdx.x * 256 + threadIdx.x;
    const int d = idx & (DINNER - 1);
    const float v = delta[idx] + bias[d];
    delta[idx] = (v > 20.f) ? v : log1pf(expf(v));
}

// ---------------------------------------------------------------------------
// Chunk-parallel selective scan (unchanged) -> bf16 y for out_proj.
// ---------------------------------------------------------------------------
__global__ __launch_bounds__(512)
void ssm_scan_chunked(const float* __restrict__ delta,
                      const float* __restrict__ xc,
                      const float* __restrict__ xdbl,
                      const float* __restrict__ xz,
                      const float* __restrict__ alog,
                      const float* __restrict__ dsk,
                      __hip_bfloat16* __restrict__ y) {
    const int d = blockIdx.x;
    const int t = threadIdx.x;
    const int s = t & 15;
    const int c = t >> 4;

    __shared__ float sdl[L_SEQ];
    __shared__ float sxl[L_SEQ];
    __shared__ float saprod[NCHUNK][DSTATE];
    __shared__ float shloc[NCHUNK][DSTATE];
    __shared__ float shstart[NCHUNK][DSTATE];

    for (int l = t; l < L_SEQ; l += 512) {
        sdl[l] = delta[(size_t)l * DINNER + d];
        sxl[l] = xc[(size_t)l * DINNER + d];
    }
    __syncthreads();

    const float A  = -expf(alog[d * DSTATE + s]);
    const int   l0 = c * CHUNK;

    float aprod = 1.f, h = 0.f;
    #pragma unroll 4
    for (int j = 0; j < CHUNK; ++j) {
        const int l = l0 + j;
        const float dl = sdl[l];
        const float Bl = xdbl[(size_t)l * NXP + DTRANK + s];
        const float da = __expf(dl * A);
        h = da * h + dl * Bl * sxl[l];
        aprod *= da;
    }
    saprod[c][s] = aprod;
    shloc[c][s]  = h;
    __syncthreads();

    if (c == 0) {
        float hs = 0.f;
        for (int cc = 0; cc < NCHUNK; ++cc) {
            shstart[cc][s] = hs;
            hs = saprod[cc][s] * hs + shloc[cc][s];
        }
    }
    __syncthreads();

    h = shstart[c][s];
    const float Dk = dsk[d];
    for (int j = 0; j < CHUNK; ++j) {
        const int l = l0 + j;
        const float dl = sdl[l];
        const float xl = sxl[l];
        const float Bl = xdbl[(size_t)l * NXP + DTRANK + s];
        const float Cl = xdbl[(size_t)l * NXP + DTRANK + DSTATE + s];
        h = __expf(dl * A) * h + dl * Bl * xl;
        float cch = h * Cl;
        cch += __shfl_xor(cch, 1, 16);
        cch += __shfl_xor(cch, 2, 16);
        cch += __shfl_xor(cch, 4, 16);
        cch += __shfl_xor(cch, 8, 16);
        if (s == 0) {
            const float zl  = xz[(size_t)l * (2 * DINNER) + DINNER + d];
            const float sig = 1.f / (1.f + __expf(-zl));
            y[(size_t)l * DINNER + d] =
                __float2bfloat16((cch + xl * Dk) * (zl * sig));
        }
    }
}

// ---------------------------------------------------------------------------
extern "C" void kernel_launch(void* const* d_in, const int* in_sizes, int n_in,
                              void* d_out, int out_size, void* d_ws, size_t ws_size,
                              hipStream_t stream) {
    const float* input   = (const float*)d_in[0];
    const float* input_w = (const float*)d_in[2];
    const float* norm_w  = (const float*)d_in[3];
    const float* norm_b  = (const float*)d_in[4];
    const float* ipw     = (const float*)d_in[5];
    const float* cw      = (const float*)d_in[6];
    const float* cb      = (const float*)d_in[7];
    const float* xpw     = (const float*)d_in[8];
    const float* dtw     = (const float*)d_in[9];
    const float* dtb     = (const float*)d_in[10];
    const float* alog    = (const float*)d_in[11];
    const float* dsk     = (const float*)d_in[12];
    const float* opw     = (const float*)d_in[13];
    float* out = (float*)d_out;

    float* ws    = (float*)d_ws;
    float* h     = ws;                         // 1M floats
    float* res   = h     + (1u << 20);         // 1M
    float* xz    = res   + (1u << 20);         // 4M
    float* xc    = xz    + (4u << 20);         // 2M
    float* xdbl  = xc    + (2u << 20);         // L*96
    float* delta = xdbl  + (L_SEQ * NXP);      // 2M
    __hip_bfloat16* hn_bf  = (__hip_bfloat16*)(delta + (2u << 20));   // 1M halfs
    __hip_bfloat16* y_bf   = hn_bf  + (1u << 20);                     // 2M halfs
    __hip_bfloat16* ipw_bf = y_bf   + (2u << 20);                     // 4M halfs
    __hip_bfloat16* opw_bf = ipw_bf + (4u << 20);                     // 2M halfs

    const dim3 blk(256);

    // h = input @ input_w^T   (M=1024, N=1024, K=512), fp32 (runs once)
    gemm_nt<<<dim3(DMODEL / 64, L_SEQ / 64), blk, 0, stream>>>(
        input, input_w, h, L_SEQ, DMODEL, 512, 512, 512, DMODEL);

    for (int i = 0; i < 4; ++i) {
        cast_f32_bf16<<<(2 * DINNER * DMODEL / 4 + 255) / 256, blk, 0, stream>>>(
            ipw + (size_t)i * 2 * DINNER * DMODEL, ipw_bf, 2 * DINNER * DMODEL / 4);

        add_ln<<<L_SEQ, 256, 0, stream>>>(
            h, res, hn_bf, norm_w + i * DMODEL, norm_b + i * DMODEL, i == 0);

        // xz = hn @ ipw^T   (M=1024, N=4096, K=1024)  bf16 MFMA
        gemm_bt_bf16<<<dim3(2 * DINNER / 128, L_SEQ / 128), blk, 0, stream>>>(
            hn_bf, ipw_bf, xz, DMODEL, DMODEL, DMODEL, 2 * DINNER);

        conv_silu<<<(L_SEQ * DINNER) / 256, 256, 0, stream>>>(
            xz, xc, cw + i * DINNER * 4, cb + i * DINNER);

        // xdbl = xc @ xpw^T   (M=1024, N=96, K=2048)  fp32 split-K x8
        zero_f32<<<(L_SEQ * NXP + 255) / 256, blk, 0, stream>>>(xdbl, L_SEQ * NXP);
        gemm_nt_splitk<<<dim3(2, L_SEQ / 64, 8), blk, 0, stream>>>(
            xc, xpw + (size_t)i * NXP * DINNER, xdbl,
            L_SEQ, NXP, DINNER, DINNER, DINNER, NXP, DINNER / 8);

        // delta = xdbl[:, :64] @ dtw^T   (M=1024, N=2048, K=64)  fp32
        gemm_nt<<<dim3(DINNER / 64, L_SEQ / 64), blk, 0, stream>>>(
            xdbl, dtw + (size_t)i * DINNER * DTRANK, delta,
            L_SEQ, DINNER, DTRANK, NXP, DTRANK, DINNER);

        softplus_bias<<<(L_SEQ * DINNER) / 256, 256, 0, stream>>>(
            delta, dtb + i * DINNER);

        ssm_scan_chunked<<<DINNER, 512, 0, stream>>>(
            delta, xc, xdbl, xz, alog + i * DINNER * DSTATE, dsk + i * DINNER, y_bf);

        // out = y @ opw^T   (M=1024, N=1024, K=2048)  bf16 MFMA
        cast_f32_bf16<<<(DMODEL * DINNER / 4 + 255) / 256, blk, 0, stream>>>(
            opw + (size_t)i * DMODEL * DINNER, opw_bf, DMODEL * DINNER / 4);
        float* dst = (i == 3) ? out : h;
        gemm_bt_bf16<<<dim3(DMODEL / 128, L_SEQ / 128), blk, 0, stream>>>(
            y_bf, opw_bf, dst, DINNER, DINNER, DINNER, DMODEL);
    }
}